// Round 6
// baseline (431.823 us; speedup 1.0000x reference)
//
#include <hip/hip_runtime.h>

// NODEModel MFMA fp16, R6: ZERO-BARRIER kernel.
// lds_w eliminated: A-fragments (weights, frag-linear layout from prep) are
// loaded straight from global as per-lane global_load_dwordx4 (L2-hot, ~200cy,
// hidden by 4 waves/SIMD of independent work). H is wave-private (each wave
// touches only its own 32-sample slab, incl. the output layer) -> not a single
// __syncthreads in the main kernel. LDS = 32 KB H only -> 4+ blocks/CU.
// Everything else as R5: tanh scale folded into weights by prep, bias as
// MFMA C-init (loaded just-in-time), v_cvt_pkrtz packing, XOR-swizzled H.

#define NTHREADS 256
#define MLP_STRIDE 53248   // fp16 elems per MLP: 4096 WinA + 3*16384 Wh
#define WINA_ELEMS 4096
#define WH_ELEMS 16384
#define TANH_SCALE 2.8853900817779268f   // 2*log2(e)

typedef _Float16 f16;
typedef f16 f16x8 __attribute__((ext_vector_type(8)));
typedef __fp16 fp16x2 __attribute__((ext_vector_type(2)));
typedef float f32x4 __attribute__((ext_vector_type(4)));

// ---------------- prep: fp32 weights -> fp16 fragment-linear (pre-scaled) ----
// Also writes 2*log2e-scaled hidden biases as fp32 at wsw + 2*MLP_STRIDE.
__global__ __launch_bounds__(NTHREADS)
void prep_kernel(const float* __restrict__ dp_Win, const float* __restrict__ dp_bin,
                 const float* __restrict__ dp_Wh,  const float* __restrict__ dp_bh,
                 const float* __restrict__ ic_Win, const float* __restrict__ ic_bin,
                 const float* __restrict__ ic_Wh,  const float* __restrict__ ic_bh,
                 f16* __restrict__ wsw)
{
    int e = blockIdx.x * NTHREADS + threadIdx.x;
    if (e >= 2 * MLP_STRIDE + 768) return;
    if (e >= 2 * MLP_STRIDE) {          // scaled hidden biases, fp32
        int idx = e - 2 * MLP_STRIDE;   // [mlp(2)][l(3)][m(128)]
        int mlp = idx / 384, rem = idx % 384;
        const float* bh = mlp ? ic_bh : dp_bh;
        float* bsc = (float*)(wsw + 2 * MLP_STRIDE);
        bsc[idx] = bh[rem] * TANH_SCALE;
        return;
    }
    int mlp = (e >= MLP_STRIDE) ? 1 : 0;   // 0 = dp, 1 = ic
    int r = e - mlp * MLP_STRIDE;
    const float* Win = mlp ? ic_Win : dp_Win;
    const float* bin = mlp ? ic_bin : dp_bin;
    const float* Wh  = mlp ? ic_Wh  : dp_Wh;
    int din = mlp ? 5 : 6;
    float val;
    if (r < WINA_ELEMS) {
        int mt = r >> 9, lane = (r >> 3) & 63, j = r & 7;
        int m = mt * 16 + (lane & 15);
        int k = ((lane >> 4) << 3) + j;                     // 0..31
        val = (k < din) ? Win[k * 128 + m] : ((k == din) ? bin[m] : 0.0f);
    } else {
        int r2 = r - WINA_ELEMS;
        int l = r2 >> 14, r3 = r2 & 16383;
        int ks = r3 >> 12, mt = (r3 >> 9) & 7, lane = (r3 >> 3) & 63, j = r3 & 7;
        int m = mt * 16 + (lane & 15);
        int k = ks * 32 + ((lane >> 4) << 3) + j;           // 0..127
        val = Wh[(l * 128 + k) * 128 + m];
    }
    wsw[e] = (f16)(val * TANH_SCALE);
}

// ---------------- main ----------------
__device__ __forceinline__ float tanh_fast(float x) {
    // input pre-scaled by 2*log2e: tanh = 1 - 2/(exp2(x)+1)
    float e = __builtin_amdgcn_exp2f(x);
    float r = __builtin_amdgcn_rcpf(e + 1.0f);
    return fmaf(-2.0f, r, 1.0f);
}

__device__ __forceinline__ unsigned int pk16(float a, float b) {
    union { fp16x2 h; unsigned int u; } c;
    c.h = __builtin_amdgcn_cvt_pkrtz(a, b);
    return c.u;
}

// XOR-swizzled H address (used only in the small output-layer section).
__device__ __forceinline__ int h_addr(int n, int kb) {
    return n * 256 + ((((kb >> 4) ^ (n & 7)) << 4) | (kb & 15));
}

__device__ __forceinline__ f32x4 mfma16(f16x8 a, f16x8 b, f32x4 c) {
    return __builtin_amdgcn_mfma_f32_16x16x32_f16(a, b, c, 0, 0, 0);
}

__global__ __launch_bounds__(NTHREADS, 4)
void node_main(const float* __restrict__ tx, const f16* __restrict__ wsw,
               const float* __restrict__ dp_Wout, const float* __restrict__ dp_bout,
               const float* __restrict__ ic_Wout, const float* __restrict__ ic_bout,
               float* __restrict__ out)
{
    __shared__ __align__(16) unsigned char lds_h[32768];

    const int tid  = threadIdx.x;
    const int lane = tid & 63;
    const int wv   = tid >> 6;
    const int q    = lane >> 4;
    const int l15  = lane & 15;
    const int p0   = blockIdx.x * 128;
    const int n0   = wv * 32 + l15;      // sample for hh-half 0 (B-frag col)

    // ---- precomputed, chain/layer-invariant LDS addresses ----
    const int d   = l15 & 7;             // XOR key (row n0 and n0+16 share it)
    const int e2  = q >> 1;
    const int par = (q & 1) << 3;
    int waddr[8];                        // H write base, feat-tile mt, hh=0
    #pragma unroll
    for (int mt = 0; mt < 8; ++mt)
        waddr[mt] = n0 * 256 + ((((2 * mt + e2) ^ d) << 4) | par);
    int raddr[4];                        // H read base, k-slab ks, hh=0
    #pragma unroll
    for (int ks = 0; ks < 4; ++ks)
        raddr[ks] = n0 * 256 + (((4 * ks + q) ^ d) << 4);

    const float* bsc = (const float*)(wsw + 2 * MLP_STRIDE);  // scaled biases

    const float4* tx4 = (const float4*)tx;
    float4 t0v = tx4[p0 + n0];
    float4 t1v = tx4[p0 + n0 + 16];
    float4 tov = tx4[p0 + (tid >> 1)];

    float a0, r0, x0, y0, z0, i0;
    float a1, r1, x1, y1, z1, i1;
    float ao, io;
    {
        float xx = t0v.y, yy = t0v.z, zz = t0v.w;
        r0 = sqrtf(fmaf(xx, xx, fmaf(yy, yy, zz * zz)));
        float irs = 1.0f / fmaxf(r0, 1e-8f);
        x0 = xx * irs; y0 = yy * irs; z0 = zz * irs;
        i0 = 1.0f / (1.0f + r0);
        a0 = 0.5f * t0v.x;
    }
    {
        float xx = t1v.y, yy = t1v.z, zz = t1v.w;
        r1 = sqrtf(fmaf(xx, xx, fmaf(yy, yy, zz * zz)));
        float irs = 1.0f / fmaxf(r1, 1e-8f);
        x1 = xx * irs; y1 = yy * irs; z1 = zz * irs;
        i1 = 1.0f / (1.0f + r1);
        a1 = 0.5f * t1v.x;
    }
    {
        float xx = tov.y, yy = tov.z, zz = tov.w;
        float rr = sqrtf(fmaf(xx, xx, fmaf(yy, yy, zz * zz)));
        io = 1.0f / (1.0f + rr);
        ao = 0.5f * tov.x;
    }

    const f32x4 z4 = {0.f, 0.f, 0.f, 0.f};
    float icv = 0.0f, dsum = 0.0f;

    for (int c = 0; c < 4; ++c) {        // c=0: ic MLP; c=1..3: dp at GL node c-1
        const f16* wb       = wsw + (c == 0 ? MLP_STRIDE : 0);
        const float* bb     = bsc + (c == 0 ? 384 : 0);
        const float* Wout   = (c == 0) ? ic_Wout : dp_Wout;
        const float* bout   = (c == 0) ? ic_bout : dp_bout;
        const float tn = (c == 1) ? 0.22540333075851662f
                       : ((c == 2) ? 1.0f : 1.7745966692414834f);   // node+1

        // ---- input layer: B frags from feature registers (lanes 0..15) ----
        f16x8 b0 = {}, b1 = {};
        if (lane < 16) {
            if (c == 0) {
                b0[0] = (f16)r0; b0[1] = (f16)x0; b0[2] = (f16)y0; b0[3] = (f16)z0;
                b0[4] = (f16)i0; b0[5] = (f16)1.0f;
                b1[0] = (f16)r1; b1[1] = (f16)x1; b1[2] = (f16)y1; b1[3] = (f16)z1;
                b1[4] = (f16)i1; b1[5] = (f16)1.0f;
            } else {
                b0[0] = (f16)(a0 * tn); b0[1] = (f16)r0; b0[2] = (f16)x0; b0[3] = (f16)y0;
                b0[4] = (f16)z0; b0[5] = (f16)i0; b0[6] = (f16)1.0f;
                b1[0] = (f16)(a1 * tn); b1[1] = (f16)r1; b1[2] = (f16)x1; b1[3] = (f16)y1;
                b1[4] = (f16)z1; b1[5] = (f16)i1; b1[6] = (f16)1.0f;
            }
        }

        // ---- input layer: A frags straight from global (frag-linear) ----
        const f16x8* Ag = (const f16x8*)wb;
        f32x4 acc[8][2];
        #pragma unroll
        for (int mt = 0; mt < 8; ++mt) {
            f16x8 a = Ag[mt * 64 + lane];
            acc[mt][0] = mfma16(a, b0, z4);      // bin folded into A k=din slot
            acc[mt][1] = mfma16(a, b1, z4);
        }
        #pragma unroll
        for (int mt = 0; mt < 8; ++mt) {
            #pragma unroll
            for (int hh = 0; hh < 2; ++hh) {
                f32x4 v = acc[mt][hh];
                uint2 o;
                o.x = pk16(tanh_fast(v[0]), tanh_fast(v[1]));
                o.y = pk16(tanh_fast(v[2]), tanh_fast(v[3]));
                *(uint2*)(lds_h + waddr[mt] + hh * 4096) = o;
            }
        }

        // ---- 3 hidden layers, weights direct from global (no barriers) ----
        for (int l = 0; l < 3; ++l) {
            const f16x8* Wg = (const f16x8*)(wb + WINA_ELEMS + l * WH_ELEMS);
            const float* bl = bb + l * 128;
            #pragma unroll
            for (int ks = 0; ks < 4; ++ks) {
                f16x8 hb0 = *(const f16x8*)(lds_h + raddr[ks]);
                f16x8 hb1 = *(const f16x8*)(lds_h + raddr[ks] + 4096);
                #pragma unroll
                for (int mt = 0; mt < 8; ++mt) {
                    f16x8 a = Wg[(ks * 8 + mt) * 64 + lane];
                    if (ks == 0) {
                        f32x4 b4 = *(const f32x4*)(bl + mt * 16 + q * 4);
                        acc[mt][0] = mfma16(a, hb0, b4);     // bias as C-init
                        acc[mt][1] = mfma16(a, hb1, b4);
                    } else {
                        acc[mt][0] = mfma16(a, hb0, acc[mt][0]);
                        acc[mt][1] = mfma16(a, hb1, acc[mt][1]);
                    }
                }
            }
            #pragma unroll
            for (int mt = 0; mt < 8; ++mt) {
                #pragma unroll
                for (int hh = 0; hh < 2; ++hh) {
                    f32x4 v = acc[mt][hh];
                    uint2 o;
                    o.x = pk16(tanh_fast(v[0]), tanh_fast(v[1]));
                    o.y = pk16(tanh_fast(v[2]), tanh_fast(v[3]));
                    *(uint2*)(lds_h + waddr[mt] + hh * 4096) = o;
                }
            }
        }

        // ---- output layer: VALU dot, 2 threads per sample (wave-local H) ----
        {
            int s  = tid >> 1;
            int hf = tid & 1;
            const float* wp = Wout + hf * 64;
            float sum = 0.0f;
            #pragma unroll
            for (int u = 0; u < 8; ++u) {
                f16x8 hv = *(const f16x8*)(lds_h + h_addr(s, hf * 128 + u * 16));
                f32x4 w0 = *(const f32x4*)(wp + u * 8);
                f32x4 w1 = *(const f32x4*)(wp + u * 8 + 4);
                sum = fmaf((float)hv[0], w0[0], sum);
                sum = fmaf((float)hv[1], w0[1], sum);
                sum = fmaf((float)hv[2], w0[2], sum);
                sum = fmaf((float)hv[3], w0[3], sum);
                sum = fmaf((float)hv[4], w1[0], sum);
                sum = fmaf((float)hv[5], w1[1], sum);
                sum = fmaf((float)hv[6], w1[2], sum);
                sum = fmaf((float)hv[7], w1[3], sum);
            }
            sum += __shfl_xor(sum, 1, 64);
            float val = sum + bout[0];
            if (c == 0) icv = val;
            else        dsum = fmaf((c == 2) ? (8.0f / 9.0f) : (5.0f / 9.0f), val, dsum);
        }
    }

    if ((tid & 1) == 0) {
        out[p0 + (tid >> 1)] = (icv + ao * dsum) * io;
    }
}

extern "C" void kernel_launch(void* const* d_in, const int* in_sizes, int n_in,
                              void* d_out, int out_size, void* d_ws, size_t ws_size,
                              hipStream_t stream) {
    const float* tx      = (const float*)d_in[0];
    const float* dp_Win  = (const float*)d_in[1];
    const float* dp_bin  = (const float*)d_in[2];
    const float* dp_Wh   = (const float*)d_in[3];
    const float* dp_bh   = (const float*)d_in[4];
    const float* dp_Wout = (const float*)d_in[5];
    const float* dp_bout = (const float*)d_in[6];
    const float* ic_Win  = (const float*)d_in[7];
    const float* ic_bin  = (const float*)d_in[8];
    const float* ic_Wh   = (const float*)d_in[9];
    const float* ic_bh   = (const float*)d_in[10];
    const float* ic_Wout = (const float*)d_in[11];
    const float* ic_bout = (const float*)d_in[12];
    float* out = (float*)d_out;
    f16* wsw = (f16*)d_ws;

    int n = in_sizes[0] / 4;

    prep_kernel<<<dim3((2 * MLP_STRIDE + 768 + NTHREADS - 1) / NTHREADS), dim3(NTHREADS), 0, stream>>>(
        dp_Win, dp_bin, dp_Wh, dp_bh, ic_Win, ic_bin, ic_Wh, ic_bh, wsw);

    node_main<<<dim3(n / 128), dim3(NTHREADS), 0, stream>>>(
        tx, wsw, dp_Wout, dp_bout, ic_Wout, ic_bout, out);
}

// Round 7
// 325.414 us; speedup vs baseline: 1.3270x; 1.3270x over previous
//
#include <hip/hip_runtime.h>

// NODEModel MFMA fp16, R7 = R6 (zero-barrier) with launch_bounds fixed.
// R6's (256,4) bound clamped VGPRs to 64 -> accumulator spill to scratch
// (WRITE_SIZE 195MB). (256,3) gives the allocator ~168 regs headroom; actual
// need ~84-100 -> no spill, and occupancy is LDS-capped at 5 blocks/CU.
// Structure: weights (frag-linear, prep-swizzled, tanh-scale folded) loaded
// per-lane straight from global (L1/L2-hot); H wave-private in 32 KB LDS
// (XOR-swizzled); bias as MFMA C-init; zero __syncthreads.

#define NTHREADS 256
#define MLP_STRIDE 53248   // fp16 elems per MLP: 4096 WinA + 3*16384 Wh
#define WINA_ELEMS 4096
#define WH_ELEMS 16384
#define TANH_SCALE 2.8853900817779268f   // 2*log2(e)

typedef _Float16 f16;
typedef f16 f16x8 __attribute__((ext_vector_type(8)));
typedef __fp16 fp16x2 __attribute__((ext_vector_type(2)));
typedef float f32x4 __attribute__((ext_vector_type(4)));

// ---------------- prep: fp32 weights -> fp16 fragment-linear (pre-scaled) ----
// Also writes 2*log2e-scaled hidden biases as fp32 at wsw + 2*MLP_STRIDE.
__global__ __launch_bounds__(NTHREADS)
void prep_kernel(const float* __restrict__ dp_Win, const float* __restrict__ dp_bin,
                 const float* __restrict__ dp_Wh,  const float* __restrict__ dp_bh,
                 const float* __restrict__ ic_Win, const float* __restrict__ ic_bin,
                 const float* __restrict__ ic_Wh,  const float* __restrict__ ic_bh,
                 f16* __restrict__ wsw)
{
    int e = blockIdx.x * NTHREADS + threadIdx.x;
    if (e >= 2 * MLP_STRIDE + 768) return;
    if (e >= 2 * MLP_STRIDE) {          // scaled hidden biases, fp32
        int idx = e - 2 * MLP_STRIDE;   // [mlp(2)][l(3)][m(128)]
        int mlp = idx / 384, rem = idx % 384;
        const float* bh = mlp ? ic_bh : dp_bh;
        float* bsc = (float*)(wsw + 2 * MLP_STRIDE);
        bsc[idx] = bh[rem] * TANH_SCALE;
        return;
    }
    int mlp = (e >= MLP_STRIDE) ? 1 : 0;   // 0 = dp, 1 = ic
    int r = e - mlp * MLP_STRIDE;
    const float* Win = mlp ? ic_Win : dp_Win;
    const float* bin = mlp ? ic_bin : dp_bin;
    const float* Wh  = mlp ? ic_Wh  : dp_Wh;
    int din = mlp ? 5 : 6;
    float val;
    if (r < WINA_ELEMS) {
        int mt = r >> 9, lane = (r >> 3) & 63, j = r & 7;
        int m = mt * 16 + (lane & 15);
        int k = ((lane >> 4) << 3) + j;                     // 0..31
        val = (k < din) ? Win[k * 128 + m] : ((k == din) ? bin[m] : 0.0f);
    } else {
        int r2 = r - WINA_ELEMS;
        int l = r2 >> 14, r3 = r2 & 16383;
        int ks = r3 >> 12, mt = (r3 >> 9) & 7, lane = (r3 >> 3) & 63, j = r3 & 7;
        int m = mt * 16 + (lane & 15);
        int k = ks * 32 + ((lane >> 4) << 3) + j;           // 0..127
        val = Wh[(l * 128 + k) * 128 + m];
    }
    wsw[e] = (f16)(val * TANH_SCALE);
}

// ---------------- main ----------------
__device__ __forceinline__ float tanh_fast(float x) {
    // input pre-scaled by 2*log2e: tanh = 1 - 2/(exp2(x)+1)
    float e = __builtin_amdgcn_exp2f(x);
    float r = __builtin_amdgcn_rcpf(e + 1.0f);
    return fmaf(-2.0f, r, 1.0f);
}

__device__ __forceinline__ unsigned int pk16(float a, float b) {
    union { fp16x2 h; unsigned int u; } c;
    c.h = __builtin_amdgcn_cvt_pkrtz(a, b);
    return c.u;
}

// XOR-swizzled H address (used only in the small output-layer section).
__device__ __forceinline__ int h_addr(int n, int kb) {
    return n * 256 + ((((kb >> 4) ^ (n & 7)) << 4) | (kb & 15));
}

__device__ __forceinline__ f32x4 mfma16(f16x8 a, f16x8 b, f32x4 c) {
    return __builtin_amdgcn_mfma_f32_16x16x32_f16(a, b, c, 0, 0, 0);
}

__global__ __launch_bounds__(NTHREADS, 3)
void node_main(const float* __restrict__ tx, const f16* __restrict__ wsw,
               const float* __restrict__ dp_Wout, const float* __restrict__ dp_bout,
               const float* __restrict__ ic_Wout, const float* __restrict__ ic_bout,
               float* __restrict__ out)
{
    __shared__ __align__(16) unsigned char lds_h[32768];

    const int tid  = threadIdx.x;
    const int lane = tid & 63;
    const int wv   = tid >> 6;
    const int q    = lane >> 4;
    const int l15  = lane & 15;
    const int p0   = blockIdx.x * 128;
    const int n0   = wv * 32 + l15;      // sample for hh-half 0 (B-frag col)

    // ---- precomputed, chain/layer-invariant LDS addresses ----
    const int d   = l15 & 7;             // XOR key (row n0 and n0+16 share it)
    const int e2  = q >> 1;
    const int par = (q & 1) << 3;
    int waddr[8];                        // H write base, feat-tile mt, hh=0
    #pragma unroll
    for (int mt = 0; mt < 8; ++mt)
        waddr[mt] = n0 * 256 + ((((2 * mt + e2) ^ d) << 4) | par);
    int raddr[4];                        // H read base, k-slab ks, hh=0
    #pragma unroll
    for (int ks = 0; ks < 4; ++ks)
        raddr[ks] = n0 * 256 + (((4 * ks + q) ^ d) << 4);

    const float* bsc = (const float*)(wsw + 2 * MLP_STRIDE);  // scaled biases

    const float4* tx4 = (const float4*)tx;
    float4 t0v = tx4[p0 + n0];
    float4 t1v = tx4[p0 + n0 + 16];
    float4 tov = tx4[p0 + (tid >> 1)];

    float a0, r0, x0, y0, z0, i0;
    float a1, r1, x1, y1, z1, i1;
    float ao, io;
    {
        float xx = t0v.y, yy = t0v.z, zz = t0v.w;
        r0 = sqrtf(fmaf(xx, xx, fmaf(yy, yy, zz * zz)));
        float irs = 1.0f / fmaxf(r0, 1e-8f);
        x0 = xx * irs; y0 = yy * irs; z0 = zz * irs;
        i0 = 1.0f / (1.0f + r0);
        a0 = 0.5f * t0v.x;
    }
    {
        float xx = t1v.y, yy = t1v.z, zz = t1v.w;
        r1 = sqrtf(fmaf(xx, xx, fmaf(yy, yy, zz * zz)));
        float irs = 1.0f / fmaxf(r1, 1e-8f);
        x1 = xx * irs; y1 = yy * irs; z1 = zz * irs;
        i1 = 1.0f / (1.0f + r1);
        a1 = 0.5f * t1v.x;
    }
    {
        float xx = tov.y, yy = tov.z, zz = tov.w;
        float rr = sqrtf(fmaf(xx, xx, fmaf(yy, yy, zz * zz)));
        io = 1.0f / (1.0f + rr);
        ao = 0.5f * tov.x;
    }

    const f32x4 z4 = {0.f, 0.f, 0.f, 0.f};
    float icv = 0.0f, dsum = 0.0f;

    for (int c = 0; c < 4; ++c) {        // c=0: ic MLP; c=1..3: dp at GL node c-1
        const f16* wb       = wsw + (c == 0 ? MLP_STRIDE : 0);
        const float* bb     = bsc + (c == 0 ? 384 : 0);
        const float* Wout   = (c == 0) ? ic_Wout : dp_Wout;
        const float* bout   = (c == 0) ? ic_bout : dp_bout;
        const float tn = (c == 1) ? 0.22540333075851662f
                       : ((c == 2) ? 1.0f : 1.7745966692414834f);   // node+1

        // ---- input layer: B frags from feature registers (lanes 0..15) ----
        f16x8 b0 = {}, b1 = {};
        if (lane < 16) {
            if (c == 0) {
                b0[0] = (f16)r0; b0[1] = (f16)x0; b0[2] = (f16)y0; b0[3] = (f16)z0;
                b0[4] = (f16)i0; b0[5] = (f16)1.0f;
                b1[0] = (f16)r1; b1[1] = (f16)x1; b1[2] = (f16)y1; b1[3] = (f16)z1;
                b1[4] = (f16)i1; b1[5] = (f16)1.0f;
            } else {
                b0[0] = (f16)(a0 * tn); b0[1] = (f16)r0; b0[2] = (f16)x0; b0[3] = (f16)y0;
                b0[4] = (f16)z0; b0[5] = (f16)i0; b0[6] = (f16)1.0f;
                b1[0] = (f16)(a1 * tn); b1[1] = (f16)r1; b1[2] = (f16)x1; b1[3] = (f16)y1;
                b1[4] = (f16)z1; b1[5] = (f16)i1; b1[6] = (f16)1.0f;
            }
        }

        // ---- input layer: A frags straight from global (frag-linear) ----
        const f16x8* Ag = (const f16x8*)wb;
        f32x4 acc[8][2];
        #pragma unroll
        for (int mt = 0; mt < 8; ++mt) {
            f16x8 a = Ag[mt * 64 + lane];
            acc[mt][0] = mfma16(a, b0, z4);      // bin folded into A k=din slot
            acc[mt][1] = mfma16(a, b1, z4);
        }
        #pragma unroll
        for (int mt = 0; mt < 8; ++mt) {
            #pragma unroll
            for (int hh = 0; hh < 2; ++hh) {
                f32x4 v = acc[mt][hh];
                uint2 o;
                o.x = pk16(tanh_fast(v[0]), tanh_fast(v[1]));
                o.y = pk16(tanh_fast(v[2]), tanh_fast(v[3]));
                *(uint2*)(lds_h + waddr[mt] + hh * 4096) = o;
            }
        }

        // ---- 3 hidden layers, weights direct from global (no barriers) ----
        for (int l = 0; l < 3; ++l) {
            const f16x8* Wg = (const f16x8*)(wb + WINA_ELEMS + l * WH_ELEMS);
            const float* bl = bb + l * 128;
            #pragma unroll
            for (int ks = 0; ks < 4; ++ks) {
                f16x8 hb0 = *(const f16x8*)(lds_h + raddr[ks]);
                f16x8 hb1 = *(const f16x8*)(lds_h + raddr[ks] + 4096);
                #pragma unroll
                for (int mt = 0; mt < 8; ++mt) {
                    f16x8 a = Wg[(ks * 8 + mt) * 64 + lane];
                    if (ks == 0) {
                        f32x4 b4 = *(const f32x4*)(bl + mt * 16 + q * 4);
                        acc[mt][0] = mfma16(a, hb0, b4);     // bias as C-init
                        acc[mt][1] = mfma16(a, hb1, b4);
                    } else {
                        acc[mt][0] = mfma16(a, hb0, acc[mt][0]);
                        acc[mt][1] = mfma16(a, hb1, acc[mt][1]);
                    }
                }
            }
            #pragma unroll
            for (int mt = 0; mt < 8; ++mt) {
                #pragma unroll
                for (int hh = 0; hh < 2; ++hh) {
                    f32x4 v = acc[mt][hh];
                    uint2 o;
                    o.x = pk16(tanh_fast(v[0]), tanh_fast(v[1]));
                    o.y = pk16(tanh_fast(v[2]), tanh_fast(v[3]));
                    *(uint2*)(lds_h + waddr[mt] + hh * 4096) = o;
                }
            }
        }

        // ---- output layer: VALU dot, 2 threads per sample (wave-local H) ----
        {
            int s  = tid >> 1;
            int hf = tid & 1;
            const float* wp = Wout + hf * 64;
            float sum = 0.0f;
            #pragma unroll
            for (int u = 0; u < 8; ++u) {
                f16x8 hv = *(const f16x8*)(lds_h + h_addr(s, hf * 128 + u * 16));
                f32x4 w0 = *(const f32x4*)(wp + u * 8);
                f32x4 w1 = *(const f32x4*)(wp + u * 8 + 4);
                sum = fmaf((float)hv[0], w0[0], sum);
                sum = fmaf((float)hv[1], w0[1], sum);
                sum = fmaf((float)hv[2], w0[2], sum);
                sum = fmaf((float)hv[3], w0[3], sum);
                sum = fmaf((float)hv[4], w1[0], sum);
                sum = fmaf((float)hv[5], w1[1], sum);
                sum = fmaf((float)hv[6], w1[2], sum);
                sum = fmaf((float)hv[7], w1[3], sum);
            }
            sum += __shfl_xor(sum, 1, 64);
            float val = sum + bout[0];
            if (c == 0) icv = val;
            else        dsum = fmaf((c == 2) ? (8.0f / 9.0f) : (5.0f / 9.0f), val, dsum);
        }
    }

    if ((tid & 1) == 0) {
        out[p0 + (tid >> 1)] = (icv + ao * dsum) * io;
    }
}

extern "C" void kernel_launch(void* const* d_in, const int* in_sizes, int n_in,
                              void* d_out, int out_size, void* d_ws, size_t ws_size,
                              hipStream_t stream) {
    const float* tx      = (const float*)d_in[0];
    const float* dp_Win  = (const float*)d_in[1];
    const float* dp_bin  = (const float*)d_in[2];
    const float* dp_Wh   = (const float*)d_in[3];
    const float* dp_bh   = (const float*)d_in[4];
    const float* dp_Wout = (const float*)d_in[5];
    const float* dp_bout = (const float*)d_in[6];
    const float* ic_Win  = (const float*)d_in[7];
    const float* ic_bin  = (const float*)d_in[8];
    const float* ic_Wh   = (const float*)d_in[9];
    const float* ic_bh   = (const float*)d_in[10];
    const float* ic_Wout = (const float*)d_in[11];
    const float* ic_bout = (const float*)d_in[12];
    float* out = (float*)d_out;
    f16* wsw = (f16*)d_ws;

    int n = in_sizes[0] / 4;

    prep_kernel<<<dim3((2 * MLP_STRIDE + 768 + NTHREADS - 1) / NTHREADS), dim3(NTHREADS), 0, stream>>>(
        dp_Win, dp_bin, dp_Wh, dp_bh, ic_Win, ic_bin, ic_Wh, ic_bh, wsw);

    node_main<<<dim3(n / 128), dim3(NTHREADS), 0, stream>>>(
        tx, wsw, dp_Wout, dp_bout, ic_Wout, ic_bout, out);
}

// Round 8
// 253.808 us; speedup vs baseline: 1.7014x; 1.2821x over previous
//
#include <hip/hip_runtime.h>

// NODEModel MFMA fp16, R8: software-pipelined weight ring (AITER-style).
// lds_w = 2-slot ring of 8 KB ks-slabs. Per slab:
//   s_waitcnt(vmcnt 0 + lgkm 0)  -- waits the DMA issued ONE SLAB AGO
//   s_barrier (raw, no compiler vmcnt drain)
//   issue global_load_lds for slab s+1 into the other slot
//   compute slab s (MFMA + tanh at layer ends)
// Lookahead = one compute window (~100-500 cy) covers the ~330 cy DMA latency.
// lgkm0 before the barrier guarantees other waves' ds_reads of the slot being
// overwritten are drained. Everything else identical to R5 (verified layouts):
// frag-linear W (prep pre-swizzles, tanh-scale folded), XOR-swizzled
// wave-private H (32 KB), bias as MFMA C-init, pkrtz packing.
// LDS = 32 KB H + 16 KB ring = 48 KB -> 3 blocks/CU.

#define NTHREADS 256
#define MLP_STRIDE 53248   // fp16 elems per MLP: 4096 WinA + 3*16384 Wh = 13 slabs
#define WINA_ELEMS 4096
#define WH_ELEMS 16384
#define SLAB_F16 4096      // 8 KB slab = 4096 fp16
#define TANH_SCALE 2.8853900817779268f   // 2*log2(e)

typedef _Float16 f16;
typedef f16 f16x8 __attribute__((ext_vector_type(8)));
typedef __fp16 fp16x2 __attribute__((ext_vector_type(2)));
typedef float f32x4 __attribute__((ext_vector_type(4)));

// ---------------- prep: fp32 weights -> fp16 fragment-linear (pre-scaled) ----
__global__ __launch_bounds__(NTHREADS)
void prep_kernel(const float* __restrict__ dp_Win, const float* __restrict__ dp_bin,
                 const float* __restrict__ dp_Wh,  const float* __restrict__ dp_bh,
                 const float* __restrict__ ic_Win, const float* __restrict__ ic_bin,
                 const float* __restrict__ ic_Wh,  const float* __restrict__ ic_bh,
                 f16* __restrict__ wsw)
{
    int e = blockIdx.x * NTHREADS + threadIdx.x;
    if (e >= 2 * MLP_STRIDE + 768) return;
    if (e >= 2 * MLP_STRIDE) {          // scaled hidden biases, fp32
        int idx = e - 2 * MLP_STRIDE;   // [mlp(2)][l(3)][m(128)]
        int mlp = idx / 384, rem = idx % 384;
        const float* bh = mlp ? ic_bh : dp_bh;
        float* bsc = (float*)(wsw + 2 * MLP_STRIDE);
        bsc[idx] = bh[rem] * TANH_SCALE;
        return;
    }
    int mlp = (e >= MLP_STRIDE) ? 1 : 0;   // 0 = dp, 1 = ic
    int r = e - mlp * MLP_STRIDE;
    const float* Win = mlp ? ic_Win : dp_Win;
    const float* bin = mlp ? ic_bin : dp_bin;
    const float* Wh  = mlp ? ic_Wh  : dp_Wh;
    int din = mlp ? 5 : 6;
    float val;
    if (r < WINA_ELEMS) {
        int mt = r >> 9, lane = (r >> 3) & 63, j = r & 7;
        int m = mt * 16 + (lane & 15);
        int k = ((lane >> 4) << 3) + j;                     // 0..31
        val = (k < din) ? Win[k * 128 + m] : ((k == din) ? bin[m] : 0.0f);
    } else {
        int r2 = r - WINA_ELEMS;
        int l = r2 >> 14, r3 = r2 & 16383;
        int ks = r3 >> 12, mt = (r3 >> 9) & 7, lane = (r3 >> 3) & 63, j = r3 & 7;
        int m = mt * 16 + (lane & 15);
        int k = ks * 32 + ((lane >> 4) << 3) + j;           // 0..127
        val = Wh[(l * 128 + k) * 128 + m];
    }
    wsw[e] = (f16)(val * TANH_SCALE);
}

// ---------------- main ----------------
__device__ __forceinline__ float tanh_fast(float x) {
    // input pre-scaled by 2*log2e: tanh = 1 - 2/(exp2(x)+1)
    float e = __builtin_amdgcn_exp2f(x);
    float r = __builtin_amdgcn_rcpf(e + 1.0f);
    return fmaf(-2.0f, r, 1.0f);
}

__device__ __forceinline__ unsigned int pk16(float a, float b) {
    union { fp16x2 h; unsigned int u; } c;
    c.h = __builtin_amdgcn_cvt_pkrtz(a, b);
    return c.u;
}

__device__ __forceinline__ int h_addr(int n, int kb) {
    return n * 256 + ((((kb >> 4) ^ (n & 7)) << 4) | (kb & 15));
}

__device__ __forceinline__ f32x4 mfma16(f16x8 a, f16x8 b, f32x4 c) {
    return __builtin_amdgcn_mfma_f32_16x16x32_f16(a, b, c, 0, 0, 0);
}

__device__ __forceinline__ void stage16(const void* g, void* l) {
    __builtin_amdgcn_global_load_lds((const __attribute__((address_space(1))) void*)g,
                                     (__attribute__((address_space(3))) void*)l, 16, 0, 0);
}

// s_waitcnt imm (gfx9 encoding): vm[3:0] | exp<<4 | lgkm<<8 | vm[5:4]<<14
#define WAITCNT_VM0_LGKM0 0x0070   // vmcnt=0, expcnt=7 (dc), lgkmcnt=0

__global__ __launch_bounds__(NTHREADS, 3)
void node_main(const float* __restrict__ tx, const f16* __restrict__ wsw,
               const float* __restrict__ dp_Wout, const float* __restrict__ dp_bout,
               const float* __restrict__ ic_Wout, const float* __restrict__ ic_bout,
               float* __restrict__ out)
{
    __shared__ __align__(16) unsigned char lds_h[32768];
    __shared__ __align__(16) unsigned char lds_w[2][8192];   // ring

    const int tid  = threadIdx.x;
    const int lane = tid & 63;
    const int wv   = tid >> 6;
    const int q    = lane >> 4;
    const int l15  = lane & 15;
    const int p0   = blockIdx.x * 128;
    const int n0   = wv * 32 + l15;

    // ---- precomputed, chain/layer-invariant LDS addresses ----
    const int d   = l15 & 7;
    const int e2  = q >> 1;
    const int par = (q & 1) << 3;
    int waddr[8];
    #pragma unroll
    for (int mt = 0; mt < 8; ++mt)
        waddr[mt] = n0 * 256 + ((((2 * mt + e2) ^ d) << 4) | par);
    int raddr[4];
    #pragma unroll
    for (int ks = 0; ks < 4; ++ks)
        raddr[ks] = n0 * 256 + (((4 * ks + q) ^ d) << 4);

    const float* bsc = (const float*)(wsw + 2 * MLP_STRIDE);

    const float4* tx4 = (const float4*)tx;
    float4 t0v = tx4[p0 + n0];
    float4 t1v = tx4[p0 + n0 + 16];
    float4 tov = tx4[p0 + (tid >> 1)];

    float a0, r0, x0, y0, z0, i0;
    float a1, r1, x1, y1, z1, i1;
    float ao, io;
    {
        float xx = t0v.y, yy = t0v.z, zz = t0v.w;
        r0 = sqrtf(fmaf(xx, xx, fmaf(yy, yy, zz * zz)));
        float irs = 1.0f / fmaxf(r0, 1e-8f);
        x0 = xx * irs; y0 = yy * irs; z0 = zz * irs;
        i0 = 1.0f / (1.0f + r0);
        a0 = 0.5f * t0v.x;
    }
    {
        float xx = t1v.y, yy = t1v.z, zz = t1v.w;
        r1 = sqrtf(fmaf(xx, xx, fmaf(yy, yy, zz * zz)));
        float irs = 1.0f / fmaxf(r1, 1e-8f);
        x1 = xx * irs; y1 = yy * irs; z1 = zz * irs;
        i1 = 1.0f / (1.0f + r1);
        a1 = 0.5f * t1v.x;
    }
    {
        float xx = tov.y, yy = tov.z, zz = tov.w;
        float rr = sqrtf(fmaf(xx, xx, fmaf(yy, yy, zz * zz)));
        io = 1.0f / (1.0f + rr);
        ao = 0.5f * tov.x;
    }

    const f32x4 z4 = {0.f, 0.f, 0.f, 0.f};
    float icv = 0.0f, dsum = 0.0f;
    int p = 0;

    // prologue: stage slab 0 of chain 0 (ic WinA) into slot 0
    {
        const char* g = (const char*)(wsw + MLP_STRIDE);
        stage16(g + tid * 16, &lds_w[0][0] + tid * 16);
        stage16(g + 4096 + tid * 16, &lds_w[0][0] + 4096 + tid * 16);
    }

    for (int c = 0; c < 4; ++c) {
        const f16* wb       = wsw + (c == 0 ? MLP_STRIDE : 0);
        const float* bb     = bsc + (c == 0 ? 384 : 0);
        const float* Wout   = (c == 0) ? ic_Wout : dp_Wout;
        const float* bout   = (c == 0) ? ic_bout : dp_bout;
        const float tn = (c == 1) ? 0.22540333075851662f
                       : ((c == 2) ? 1.0f : 1.7745966692414834f);   // node+1

        f32x4 acc[8][2];

        #pragma unroll 1
        for (int sw = 0; sw < 13; ++sw) {
            // ---- pipelined sync point ----
            __asm__ __volatile__("" ::: "memory");
            __builtin_amdgcn_s_waitcnt(WAITCNT_VM0_LGKM0);  // my slab-s DMA landed + my LDS ops drained
            __builtin_amdgcn_s_barrier();                   // everyone's landed / done with s-1
            __asm__ __volatile__("" ::: "memory");

            // ---- issue next slab's stage into the other slot ----
            if (!(c == 3 && sw == 12)) {
                const char* g = (sw < 12) ? (const char*)(wb + (sw + 1) * SLAB_F16)
                                          : (const char*)wsw;   // next chain = dp base
                unsigned char* dst = &lds_w[p ^ 1][0];
                stage16(g + tid * 16, dst + tid * 16);
                stage16(g + 4096 + tid * 16, dst + 4096 + tid * 16);
            }
            __asm__ __volatile__("" ::: "memory");

            const unsigned char* A = &lds_w[p][0];

            if (sw == 0) {
                // ---- input layer ----
                f16x8 b0 = {}, b1 = {};
                if (lane < 16) {
                    if (c == 0) {
                        b0[0] = (f16)r0; b0[1] = (f16)x0; b0[2] = (f16)y0; b0[3] = (f16)z0;
                        b0[4] = (f16)i0; b0[5] = (f16)1.0f;
                        b1[0] = (f16)r1; b1[1] = (f16)x1; b1[2] = (f16)y1; b1[3] = (f16)z1;
                        b1[4] = (f16)i1; b1[5] = (f16)1.0f;
                    } else {
                        b0[0] = (f16)(a0 * tn); b0[1] = (f16)r0; b0[2] = (f16)x0; b0[3] = (f16)y0;
                        b0[4] = (f16)z0; b0[5] = (f16)i0; b0[6] = (f16)1.0f;
                        b1[0] = (f16)(a1 * tn); b1[1] = (f16)r1; b1[2] = (f16)x1; b1[3] = (f16)y1;
                        b1[4] = (f16)z1; b1[5] = (f16)i1; b1[6] = (f16)1.0f;
                    }
                }
                #pragma unroll
                for (int mt = 0; mt < 8; ++mt) {
                    f16x8 a = *(const f16x8*)(A + ((mt * 64 + lane) << 4));
                    acc[mt][0] = mfma16(a, b0, z4);
                    acc[mt][1] = mfma16(a, b1, z4);
                }
                #pragma unroll
                for (int mt = 0; mt < 8; ++mt) {
                    #pragma unroll
                    for (int hh = 0; hh < 2; ++hh) {
                        f32x4 v = acc[mt][hh];
                        uint2 o;
                        o.x = pk16(tanh_fast(v[0]), tanh_fast(v[1]));
                        o.y = pk16(tanh_fast(v[2]), tanh_fast(v[3]));
                        *(uint2*)(lds_h + waddr[mt] + hh * 4096) = o;
                    }
                }
            } else {
                // ---- hidden layer slab: l = (sw-1)/4, ks = (sw-1)%4 ----
                int l  = (sw - 1) >> 2;
                int ks = (sw - 1) & 3;
                f16x8 hb0 = *(const f16x8*)(lds_h + raddr[ks]);
                f16x8 hb1 = *(const f16x8*)(lds_h + raddr[ks] + 4096);
                if (ks == 0) {
                    const float* bl = bb + l * 128;
                    #pragma unroll
                    for (int mt = 0; mt < 8; ++mt) {
                        f16x8 a = *(const f16x8*)(A + ((mt * 64 + lane) << 4));
                        f32x4 b4 = *(const f32x4*)(bl + mt * 16 + q * 4);
                        acc[mt][0] = mfma16(a, hb0, b4);
                        acc[mt][1] = mfma16(a, hb1, b4);
                    }
                } else {
                    #pragma unroll
                    for (int mt = 0; mt < 8; ++mt) {
                        f16x8 a = *(const f16x8*)(A + ((mt * 64 + lane) << 4));
                        acc[mt][0] = mfma16(a, hb0, acc[mt][0]);
                        acc[mt][1] = mfma16(a, hb1, acc[mt][1]);
                    }
                }
                if (ks == 3) {
                    #pragma unroll
                    for (int mt = 0; mt < 8; ++mt) {
                        #pragma unroll
                        for (int hh = 0; hh < 2; ++hh) {
                            f32x4 v = acc[mt][hh];
                            uint2 o;
                            o.x = pk16(tanh_fast(v[0]), tanh_fast(v[1]));
                            o.y = pk16(tanh_fast(v[2]), tanh_fast(v[3]));
                            *(uint2*)(lds_h + waddr[mt] + hh * 4096) = o;
                        }
                    }
                }
            }
            p ^= 1;
        }

        // ---- output layer: VALU dot, 2 threads per sample (wave-local H) ----
        {
            int s  = tid >> 1;
            int hf = tid & 1;
            const float* wp = Wout + hf * 64;
            float sum = 0.0f;
            #pragma unroll
            for (int u = 0; u < 8; ++u) {
                f16x8 hv = *(const f16x8*)(lds_h + h_addr(s, hf * 128 + u * 16));
                f32x4 w0 = *(const f32x4*)(wp + u * 8);
                f32x4 w1 = *(const f32x4*)(wp + u * 8 + 4);
                sum = fmaf((float)hv[0], w0[0], sum);
                sum = fmaf((float)hv[1], w0[1], sum);
                sum = fmaf((float)hv[2], w0[2], sum);
                sum = fmaf((float)hv[3], w0[3], sum);
                sum = fmaf((float)hv[4], w1[0], sum);
                sum = fmaf((float)hv[5], w1[1], sum);
                sum = fmaf((float)hv[6], w1[2], sum);
                sum = fmaf((float)hv[7], w1[3], sum);
            }
            sum += __shfl_xor(sum, 1, 64);
            float val = sum + bout[0];
            if (c == 0) icv = val;
            else        dsum = fmaf((c == 2) ? (8.0f / 9.0f) : (5.0f / 9.0f), val, dsum);
        }
    }

    if ((tid & 1) == 0) {
        out[p0 + (tid >> 1)] = (icv + ao * dsum) * io;
    }
}

extern "C" void kernel_launch(void* const* d_in, const int* in_sizes, int n_in,
                              void* d_out, int out_size, void* d_ws, size_t ws_size,
                              hipStream_t stream) {
    const float* tx      = (const float*)d_in[0];
    const float* dp_Win  = (const float*)d_in[1];
    const float* dp_bin  = (const float*)d_in[2];
    const float* dp_Wh   = (const float*)d_in[3];
    const float* dp_bh   = (const float*)d_in[4];
    const float* dp_Wout = (const float*)d_in[5];
    const float* dp_bout = (const float*)d_in[6];
    const float* ic_Win  = (const float*)d_in[7];
    const float* ic_bin  = (const float*)d_in[8];
    const float* ic_Wh   = (const float*)d_in[9];
    const float* ic_bh   = (const float*)d_in[10];
    const float* ic_Wout = (const float*)d_in[11];
    const float* ic_bout = (const float*)d_in[12];
    float* out = (float*)d_out;
    f16* wsw = (f16*)d_ws;

    int n = in_sizes[0] / 4;

    prep_kernel<<<dim3((2 * MLP_STRIDE + 768 + NTHREADS - 1) / NTHREADS), dim3(NTHREADS), 0, stream>>>(
        dp_Win, dp_bin, dp_Wh, dp_bh, ic_Win, ic_bin, ic_Wh, ic_bh, wsw);

    node_main<<<dim3(n / 128), dim3(NTHREADS), 0, stream>>>(
        tx, wsw, dp_Wout, dp_bout, ic_Wout, ic_bout, out);
}

// Round 9
// 240.378 us; speedup vs baseline: 1.7964x; 1.0559x over previous
//
#include <hip/hip_runtime.h>

// NODEModel MFMA fp16, R9: 64 samples per wave (A-read amortization).
// Per-pipe model said LDS data pipe (~5.6 GB, mostly weight A-frag re-reads)
// is the largest term. Each wave now owns 64 samples (4 B-frags, nt=0..3):
// one A-frag ds_read feeds 4 MFMAs (was 2) -> LDS traffic -35%.
// Block = 256 thr = 4 waves x 64 samples = 256 samples. H = 64 KB, ring 16 KB
// -> 80 KB LDS, 2 blocks/CU. acc = 8mt x 4nt f32x4 = 128 VGPR -> bounds (256,2).
// Out layer: 1 sample per lane, no shuffle. Ring pipeline as R8 (waitcnt+raw
// barrier). Verified layouts unchanged: frag-linear W (prep pre-swizzles,
// tanh scale folded), XOR-swizzled wave-private H, bias as MFMA C-init.

#define NTHREADS 256
#define MLP_STRIDE 53248   // fp16 elems per MLP: 4096 WinA + 3*16384 Wh = 13 slabs
#define WINA_ELEMS 4096
#define WH_ELEMS 16384
#define SLAB_F16 4096      // 8 KB slab
#define TANH_SCALE 2.8853900817779268f   // 2*log2(e)

typedef _Float16 f16;
typedef f16 f16x8 __attribute__((ext_vector_type(8)));
typedef __fp16 fp16x2 __attribute__((ext_vector_type(2)));
typedef float f32x4 __attribute__((ext_vector_type(4)));

// ---------------- prep: fp32 weights -> fp16 fragment-linear (pre-scaled) ----
__global__ __launch_bounds__(NTHREADS)
void prep_kernel(const float* __restrict__ dp_Win, const float* __restrict__ dp_bin,
                 const float* __restrict__ dp_Wh,  const float* __restrict__ dp_bh,
                 const float* __restrict__ ic_Win, const float* __restrict__ ic_bin,
                 const float* __restrict__ ic_Wh,  const float* __restrict__ ic_bh,
                 f16* __restrict__ wsw)
{
    int e = blockIdx.x * NTHREADS + threadIdx.x;
    if (e >= 2 * MLP_STRIDE + 768) return;
    if (e >= 2 * MLP_STRIDE) {          // scaled hidden biases, fp32
        int idx = e - 2 * MLP_STRIDE;   // [mlp(2)][l(3)][m(128)]
        int mlp = idx / 384, rem = idx % 384;
        const float* bh = mlp ? ic_bh : dp_bh;
        float* bsc = (float*)(wsw + 2 * MLP_STRIDE);
        bsc[idx] = bh[rem] * TANH_SCALE;
        return;
    }
    int mlp = (e >= MLP_STRIDE) ? 1 : 0;   // 0 = dp, 1 = ic
    int r = e - mlp * MLP_STRIDE;
    const float* Win = mlp ? ic_Win : dp_Win;
    const float* bin = mlp ? ic_bin : dp_bin;
    const float* Wh  = mlp ? ic_Wh  : dp_Wh;
    int din = mlp ? 5 : 6;
    float val;
    if (r < WINA_ELEMS) {
        int mt = r >> 9, lane = (r >> 3) & 63, j = r & 7;
        int m = mt * 16 + (lane & 15);
        int k = ((lane >> 4) << 3) + j;                     // 0..31
        val = (k < din) ? Win[k * 128 + m] : ((k == din) ? bin[m] : 0.0f);
    } else {
        int r2 = r - WINA_ELEMS;
        int l = r2 >> 14, r3 = r2 & 16383;
        int ks = r3 >> 12, mt = (r3 >> 9) & 7, lane = (r3 >> 3) & 63, j = r3 & 7;
        int m = mt * 16 + (lane & 15);
        int k = ks * 32 + ((lane >> 4) << 3) + j;           // 0..127
        val = Wh[(l * 128 + k) * 128 + m];
    }
    wsw[e] = (f16)(val * TANH_SCALE);
}

// ---------------- main ----------------
__device__ __forceinline__ float tanh_fast(float x) {
    // input pre-scaled by 2*log2e: tanh = 1 - 2/(exp2(x)+1)
    float e = __builtin_amdgcn_exp2f(x);
    float r = __builtin_amdgcn_rcpf(e + 1.0f);
    return fmaf(-2.0f, r, 1.0f);
}

__device__ __forceinline__ unsigned int pk16(float a, float b) {
    union { fp16x2 h; unsigned int u; } c;
    c.h = __builtin_amdgcn_cvt_pkrtz(a, b);
    return c.u;
}

__device__ __forceinline__ int h_addr(int n, int kb) {
    return n * 256 + ((((kb >> 4) ^ (n & 7)) << 4) | (kb & 15));
}

__device__ __forceinline__ f32x4 mfma16(f16x8 a, f16x8 b, f32x4 c) {
    return __builtin_amdgcn_mfma_f32_16x16x32_f16(a, b, c, 0, 0, 0);
}

__device__ __forceinline__ void stage16(const void* g, void* l) {
    __builtin_amdgcn_global_load_lds((const __attribute__((address_space(1))) void*)g,
                                     (__attribute__((address_space(3))) void*)l, 16, 0, 0);
}

#define WAITCNT_VM0_LGKM0 0x0070   // vmcnt=0, expcnt=7 (dc), lgkmcnt=0

__global__ __launch_bounds__(NTHREADS, 2)
void node_main(const float* __restrict__ tx, const f16* __restrict__ wsw,
               const float* __restrict__ dp_Wout, const float* __restrict__ dp_bout,
               const float* __restrict__ ic_Wout, const float* __restrict__ ic_bout,
               float* __restrict__ out)
{
    __shared__ __align__(16) unsigned char lds_h[65536];     // 4 waves x 64 samples x 256 B
    __shared__ __align__(16) unsigned char lds_w[2][8192];   // ring

    const int tid  = threadIdx.x;
    const int lane = tid & 63;
    const int wv   = tid >> 6;
    const int q    = lane >> 4;
    const int l15  = lane & 15;
    const int p0   = blockIdx.x * 256;
    const int n0   = wv * 64 + l15;      // sample of nt=0 B-frag col

    // ---- precomputed, chain/layer-invariant LDS addresses (nt via +4096*nt) --
    const int d   = l15 & 7;
    const int e2  = q >> 1;
    const int par = (q & 1) << 3;
    int waddr[8];
    #pragma unroll
    for (int mt = 0; mt < 8; ++mt)
        waddr[mt] = n0 * 256 + ((((2 * mt + e2) ^ d) << 4) | par);
    int raddr[4];
    #pragma unroll
    for (int ks = 0; ks < 4; ++ks)
        raddr[ks] = n0 * 256 + (((4 * ks + q) ^ d) << 4);

    const float* bsc = (const float*)(wsw + 2 * MLP_STRIDE);

    const float4* tx4 = (const float4*)tx;

    // features for the 4 B-frag sample groups (meaningful in lanes 0..15)
    float rA[4], xA[4], yA[4], zA[4], iA[4], aA[4];
    #pragma unroll
    for (int nt = 0; nt < 4; ++nt) {
        float4 tv = tx4[p0 + n0 + 16 * nt];
        float xx = tv.y, yy = tv.z, zz = tv.w;
        float rr = sqrtf(fmaf(xx, xx, fmaf(yy, yy, zz * zz)));
        float irs = 1.0f / fmaxf(rr, 1e-8f);
        rA[nt] = rr; xA[nt] = xx * irs; yA[nt] = yy * irs; zA[nt] = zz * irs;
        iA[nt] = 1.0f / (1.0f + rr);
        aA[nt] = 0.5f * tv.x;
    }
    // own sample (for output layer / combine): 1 sample per lane
    const int sown = wv * 64 + lane;
    float ao, io;
    {
        float4 tv = tx4[p0 + sown];
        float xx = tv.y, yy = tv.z, zz = tv.w;
        float rr = sqrtf(fmaf(xx, xx, fmaf(yy, yy, zz * zz)));
        io = 1.0f / (1.0f + rr);
        ao = 0.5f * tv.x;
    }

    const f32x4 z4 = {0.f, 0.f, 0.f, 0.f};
    float icv = 0.0f, dsum = 0.0f;
    int p = 0;

    // prologue: stage slab 0 of chain 0 (ic WinA) into slot 0
    {
        const char* g = (const char*)(wsw + MLP_STRIDE);
        stage16(g + tid * 16, &lds_w[0][0] + tid * 16);
        stage16(g + 4096 + tid * 16, &lds_w[0][0] + 4096 + tid * 16);
    }

    for (int c = 0; c < 4; ++c) {
        const f16* wb       = wsw + (c == 0 ? MLP_STRIDE : 0);
        const float* bb     = bsc + (c == 0 ? 384 : 0);
        const float* Wout   = (c == 0) ? ic_Wout : dp_Wout;
        const float* bout   = (c == 0) ? ic_bout : dp_bout;
        const float tn = (c == 1) ? 0.22540333075851662f
                       : ((c == 2) ? 1.0f : 1.7745966692414834f);   // node+1

        // ---- B frags for the input layer (lanes 0..15 hold real data) ----
        f16x8 bfr[4];
        #pragma unroll
        for (int nt = 0; nt < 4; ++nt) {
            f16x8 b = {};
            if (lane < 16) {
                if (c == 0) {
                    b[0] = (f16)rA[nt]; b[1] = (f16)xA[nt]; b[2] = (f16)yA[nt];
                    b[3] = (f16)zA[nt]; b[4] = (f16)iA[nt]; b[5] = (f16)1.0f;
                } else {
                    b[0] = (f16)(aA[nt] * tn); b[1] = (f16)rA[nt]; b[2] = (f16)xA[nt];
                    b[3] = (f16)yA[nt]; b[4] = (f16)zA[nt]; b[5] = (f16)iA[nt];
                    b[6] = (f16)1.0f;
                }
            }
            bfr[nt] = b;
        }

        f32x4 acc[8][4];

        #pragma unroll 1
        for (int sw = 0; sw < 13; ++sw) {
            // ---- pipelined sync point ----
            __asm__ __volatile__("" ::: "memory");
            __builtin_amdgcn_s_waitcnt(WAITCNT_VM0_LGKM0);
            __builtin_amdgcn_s_barrier();
            __asm__ __volatile__("" ::: "memory");

            // ---- issue next slab's stage into the other slot ----
            if (!(c == 3 && sw == 12)) {
                const char* g = (sw < 12) ? (const char*)(wb + (sw + 1) * SLAB_F16)
                                          : (const char*)wsw;   // next chain = dp base
                unsigned char* dst = &lds_w[p ^ 1][0];
                stage16(g + tid * 16, dst + tid * 16);
                stage16(g + 4096 + tid * 16, dst + 4096 + tid * 16);
            }
            __asm__ __volatile__("" ::: "memory");

            const unsigned char* A = &lds_w[p][0];

            if (sw == 0) {
                // ---- input layer: 8mt x 4nt MFMAs ----
                #pragma unroll
                for (int mt = 0; mt < 8; ++mt) {
                    f16x8 a = *(const f16x8*)(A + ((mt * 64 + lane) << 4));
                    #pragma unroll
                    for (int nt = 0; nt < 4; ++nt)
                        acc[mt][nt] = mfma16(a, bfr[nt], z4);
                }
                #pragma unroll
                for (int mt = 0; mt < 8; ++mt) {
                    #pragma unroll
                    for (int nt = 0; nt < 4; ++nt) {
                        f32x4 v = acc[mt][nt];
                        uint2 o;
                        o.x = pk16(tanh_fast(v[0]), tanh_fast(v[1]));
                        o.y = pk16(tanh_fast(v[2]), tanh_fast(v[3]));
                        *(uint2*)(lds_h + waddr[mt] + nt * 4096) = o;
                    }
                }
            } else {
                // ---- hidden layer slab: l = (sw-1)/4, ks = (sw-1)%4 ----
                int l  = (sw - 1) >> 2;
                int ks = (sw - 1) & 3;
                f16x8 hb[4];
                #pragma unroll
                for (int nt = 0; nt < 4; ++nt)
                    hb[nt] = *(const f16x8*)(lds_h + raddr[ks] + nt * 4096);
                if (ks == 0) {
                    const float* bl = bb + l * 128;
                    #pragma unroll
                    for (int mt = 0; mt < 8; ++mt) {
                        f16x8 a = *(const f16x8*)(A + ((mt * 64 + lane) << 4));
                        f32x4 b4 = *(const f32x4*)(bl + mt * 16 + q * 4);
                        #pragma unroll
                        for (int nt = 0; nt < 4; ++nt)
                            acc[mt][nt] = mfma16(a, hb[nt], b4);
                    }
                } else {
                    #pragma unroll
                    for (int mt = 0; mt < 8; ++mt) {
                        f16x8 a = *(const f16x8*)(A + ((mt * 64 + lane) << 4));
                        #pragma unroll
                        for (int nt = 0; nt < 4; ++nt)
                            acc[mt][nt] = mfma16(a, hb[nt], acc[mt][nt]);
                    }
                }
                if (ks == 3) {
                    #pragma unroll
                    for (int mt = 0; mt < 8; ++mt) {
                        #pragma unroll
                        for (int nt = 0; nt < 4; ++nt) {
                            f32x4 v = acc[mt][nt];
                            uint2 o;
                            o.x = pk16(tanh_fast(v[0]), tanh_fast(v[1]));
                            o.y = pk16(tanh_fast(v[2]), tanh_fast(v[3]));
                            *(uint2*)(lds_h + waddr[mt] + nt * 4096) = o;
                        }
                    }
                }
            }
            p ^= 1;
        }

        // ---- output layer: 1 sample per lane, 128-elem dot from own H ----
        {
            float sum = 0.0f;
            #pragma unroll
            for (int u = 0; u < 16; ++u) {
                f16x8 hv = *(const f16x8*)(lds_h + h_addr(sown, u * 16));
                f32x4 w0 = *(const f32x4*)(Wout + u * 8);
                f32x4 w1 = *(const f32x4*)(Wout + u * 8 + 4);
                sum = fmaf((float)hv[0], w0[0], sum);
                sum = fmaf((float)hv[1], w0[1], sum);
                sum = fmaf((float)hv[2], w0[2], sum);
                sum = fmaf((float)hv[3], w0[3], sum);
                sum = fmaf((float)hv[4], w1[0], sum);
                sum = fmaf((float)hv[5], w1[1], sum);
                sum = fmaf((float)hv[6], w1[2], sum);
                sum = fmaf((float)hv[7], w1[3], sum);
            }
            float val = sum + bout[0];
            if (c == 0) icv = val;
            else        dsum = fmaf((c == 2) ? (8.0f / 9.0f) : (5.0f / 9.0f), val, dsum);
        }
    }

    out[p0 + sown] = (icv + ao * dsum) * io;

}

extern "C" void kernel_launch(void* const* d_in, const int* in_sizes, int n_in,
                              void* d_out, int out_size, void* d_ws, size_t ws_size,
                              hipStream_t stream) {
    const float* tx      = (const float*)d_in[0];
    const float* dp_Win  = (const float*)d_in[1];
    const float* dp_bin  = (const float*)d_in[2];
    const float* dp_Wh   = (const float*)d_in[3];
    const float* dp_bh   = (const float*)d_in[4];
    const float* dp_Wout = (const float*)d_in[5];
    const float* dp_bout = (const float*)d_in[6];
    const float* ic_Win  = (const float*)d_in[7];
    const float* ic_bin  = (const float*)d_in[8];
    const float* ic_Wh   = (const float*)d_in[9];
    const float* ic_bh   = (const float*)d_in[10];
    const float* ic_Wout = (const float*)d_in[11];
    const float* ic_bout = (const float*)d_in[12];
    float* out = (float*)d_out;
    f16* wsw = (f16*)d_ws;

    int n = in_sizes[0] / 4;

    prep_kernel<<<dim3((2 * MLP_STRIDE + 768 + NTHREADS - 1) / NTHREADS), dim3(NTHREADS), 0, stream>>>(
        dp_Win, dp_bin, dp_Wh, dp_bh, ic_Win, ic_bin, ic_Wh, ic_bh, wsw);

    node_main<<<dim3(n / 256), dim3(NTHREADS), 0, stream>>>(
        tx, wsw, dp_Wout, dp_bout, ic_Wout, ic_bout, out);
}